// Round 7
// baseline (908.054 us; speedup 1.0000x reference)
//
#include <hip/hip_runtime.h>
#include <hip/hip_bf16.h>

#define N_OBJ 8192
#define N_REL 32768
#define HID   512
#define POOL  4096
#define NOC   151
#define NRC   51

typedef __bf16 bf16_t;
typedef __attribute__((ext_vector_type(8))) __bf16 bf16x8;
typedef __attribute__((ext_vector_type(4))) __bf16 bf16x4;
typedef __attribute__((ext_vector_type(4))) float f32x4;

// Async global->LDS, 16B per lane. LDS dest semantics: wave-uniform base + lane*16.
__device__ __forceinline__ void async_copy16(const void* g, void* l) {
    __builtin_amdgcn_global_load_lds((__attribute__((address_space(1))) void*)g,
                                     (__attribute__((address_space(3))) void*)l,
                                     16, 0, 0);
}

// ---------------- prep: all transposes + bf16 convert in ONE launch ----------------
// blocks 0..511      : W_emb  [512][1024]  -> Wemb_t [1024][512]
// blocks 512..4607   : W_cat  [1024][4096] -> Wcat_t [4096][1024]
// blocks 4608..4863  : W_ctx  [4096][51]   -> Wctx_t [64][4096] (zero-padded)
// blocks 4864..6911  : edge_ctx f32 -> ecb bf16 (grid-stride)

__global__ void prep_kernel(const float* __restrict__ W_emb, bf16_t* __restrict__ Wemb_t,
                            const float* __restrict__ W_cat, bf16_t* __restrict__ Wcat_t,
                            const float* __restrict__ W_ctx, bf16_t* __restrict__ Wctx_t,
                            const float* __restrict__ ec,    bf16_t* __restrict__ ecb) {
    const int bid = blockIdx.x;
    if (bid >= 4864) {   // convert task
        const int tid = threadIdx.y * 32 + threadIdx.x;
        int i = (bid - 4864) * 256 + tid;
        const int n4 = N_OBJ * HID / 4;
        const int stride = 2048 * 256;
        for (; i < n4; i += stride) {
            float4 v = ((const float4*)ec)[i];
            bf16x4 o;
            o[0] = (bf16_t)v.x; o[1] = (bf16_t)v.y; o[2] = (bf16_t)v.z; o[3] = (bf16_t)v.w;
            ((bf16x4*)ecb)[i] = o;
        }
        return;
    }
    const float* in; bf16_t* outp; int K, C, Cpad, cb, kb;
    if (bid < 512)       { in = W_emb; outp = Wemb_t; K = HID;  C = 1024; Cpad = 1024;
                           cb = (bid & 31) << 5; kb = (bid >> 5) << 5; }
    else if (bid < 4608) { int b = bid - 512;  in = W_cat; outp = Wcat_t; K = 1024; C = POOL; Cpad = POOL;
                           cb = (b & 127) << 5; kb = (b >> 7) << 5; }
    else                 { int b = bid - 4608; in = W_ctx; outp = Wctx_t; K = POOL; C = NRC;  Cpad = 64;
                           cb = (b & 1) << 5;  kb = (b >> 1) << 5; }
    __shared__ float tile[32][33];
    const int tx = threadIdx.x, ty = threadIdx.y; // 32 x 8
    #pragma unroll
    for (int i = 0; i < 32; i += 8) {
        int k = kb + ty + i, c = cb + tx;
        float v = (k < K && c < C) ? in[(size_t)k * C + c] : 0.0f;
        tile[ty + i][tx] = v;
    }
    __syncthreads();
    #pragma unroll
    for (int i = 0; i < 32; i += 8) {
        int c = cb + ty + i, k = kb + tx;
        if (c < Cpad && k < K) outp[(size_t)c * K + k] = (bf16_t)tile[tx][ty + i];
    }
}

// ---------------- GEMM1: C1 = relu(ec @ Wemb + b), bf16 out [8192][1024] ----------------
// (unchanged, known-good)

__global__ __launch_bounds__(256, 2) void gemm1_kernel(
    const bf16_t* __restrict__ A,    // [8192][512]
    const bf16_t* __restrict__ Bt,   // [1024][512]
    const float* __restrict__ bias,  // [1024]
    bf16_t* __restrict__ C)          // [8192][1024]
{
    __shared__ __align__(16) bf16_t As[128 * 64];
    __shared__ __align__(16) bf16_t Bs[128 * 64];
    const int tid = threadIdx.x;
    const int w = tid >> 6, lane = tid & 63;
    const int m0 = blockIdx.x * 128, n0 = blockIdx.y * 128;
    const int lrow = tid >> 3, lcs = tid & 7;
    const int wm = w & 1, wn = w >> 1;
    const int quad = lane >> 4, l16 = lane & 15;
    f32x4 acc[4][4] = {};

    for (int kt = 0; kt < HID / 64; ++kt) {
        const int k0 = kt * 64;
        #pragma unroll
        for (int j = 0; j < 4; ++j) {
            int ml = j * 32 + lrow;
            int cg = lcs ^ (ml & 7);
            async_copy16(A + (size_t)(m0 + ml) * HID + k0 + cg * 8, &As[ml * 64 + lcs * 8]);
        }
        #pragma unroll
        for (int j = 0; j < 4; ++j) {
            int nl = j * 32 + lrow;
            int cg = lcs ^ (nl & 7);
            async_copy16(Bt + (size_t)(n0 + nl) * HID + k0 + cg * 8, &Bs[nl * 64 + lcs * 8]);
        }
        __syncthreads();
        #pragma unroll
        for (int kb = 0; kb < 2; ++kb) {
            bf16x8 a[4], b[4];
            #pragma unroll
            for (int i = 0; i < 4; ++i) {
                int m = wm * 64 + i * 16 + l16;
                int ch = (kb * 4 + quad) ^ (m & 7);
                a[i] = *(const bf16x8*)&As[m * 64 + ch * 8];
            }
            #pragma unroll
            for (int i = 0; i < 4; ++i) {
                int n = wn * 64 + i * 16 + l16;
                int ch = (kb * 4 + quad) ^ (n & 7);
                b[i] = *(const bf16x8*)&Bs[n * 64 + ch * 8];
            }
            #pragma unroll
            for (int i = 0; i < 4; ++i)
                #pragma unroll
                for (int jj = 0; jj < 4; ++jj)
                    acc[i][jj] = __builtin_amdgcn_mfma_f32_16x16x32_bf16(a[i], b[jj], acc[i][jj], 0, 0, 0);
        }
        __syncthreads();
    }
    #pragma unroll
    for (int i = 0; i < 4; ++i) {
        int rbase = m0 + wm * 64 + i * 16 + quad * 4;
        #pragma unroll
        for (int jj = 0; jj < 4; ++jj) {
            int c = n0 + wn * 64 + jj * 16 + l16;
            float bv = bias[c];
            #pragma unroll
            for (int rr = 0; rr < 4; ++rr) {
                float v = acc[i][jj][rr] + bv;
                v = fmaxf(v, 0.0f);
                C[(size_t)(rbase + rr) * 1024 + c] = (bf16_t)v;
            }
        }
    }
}

// ---------------- GEMM1b: HW = C1[:, 0:512] @ Wcat[0:512, :],  TW = C1[:,512:] @ Wcat[512:,:] ----
// (unchanged, known-good). prod_rep[r] = HW[i0[r]] + TW[i1[r]] + b_cat.

__global__ __launch_bounds__(256, 2) void gemm_half_kernel(
    const bf16_t* __restrict__ C1,     // [8192][1024]
    const bf16_t* __restrict__ Wcat_t, // [4096][1024]
    bf16_t* __restrict__ HWb,          // [8192][4096]
    bf16_t* __restrict__ TWb)          // [8192][4096]
{
    __shared__ __align__(16) bf16_t As[128 * 64];
    __shared__ __align__(16) bf16_t Bs[128 * 64];
    const int tid = threadIdx.x;
    const int w = tid >> 6, lane = tid & 63;
    const int m0 = blockIdx.x * 128, n0 = blockIdx.y * 128;
    const int koff = blockIdx.z * 512;
    bf16_t* const Cout = blockIdx.z ? TWb : HWb;
    const int lrow = tid >> 3, lcs = tid & 7;
    const int wm = w & 1, wn = w >> 1;
    const int quad = lane >> 4, l16 = lane & 15;
    f32x4 acc[4][4] = {};

    for (int kt = 0; kt < 8; ++kt) {   // K = 512
        const int k0 = koff + kt * 64;
        #pragma unroll
        for (int j = 0; j < 4; ++j) {
            int ml = j * 32 + lrow;
            int cg = lcs ^ (ml & 7);
            async_copy16(C1 + (size_t)(m0 + ml) * 1024 + k0 + cg * 8, &As[ml * 64 + lcs * 8]);
        }
        #pragma unroll
        for (int j = 0; j < 4; ++j) {
            int nl = j * 32 + lrow;
            int cg = lcs ^ (nl & 7);
            async_copy16(Wcat_t + (size_t)(n0 + nl) * 1024 + k0 + cg * 8, &Bs[nl * 64 + lcs * 8]);
        }
        __syncthreads();
        #pragma unroll
        for (int kb = 0; kb < 2; ++kb) {
            bf16x8 a[4], b[4];
            #pragma unroll
            for (int i = 0; i < 4; ++i) {
                int m = wm * 64 + i * 16 + l16;
                int ch = (kb * 4 + quad) ^ (m & 7);
                a[i] = *(const bf16x8*)&As[m * 64 + ch * 8];
            }
            #pragma unroll
            for (int i = 0; i < 4; ++i) {
                int n = wn * 64 + i * 16 + l16;
                int ch = (kb * 4 + quad) ^ (n & 7);
                b[i] = *(const bf16x8*)&Bs[n * 64 + ch * 8];
            }
            #pragma unroll
            for (int i = 0; i < 4; ++i)
                #pragma unroll
                for (int jj = 0; jj < 4; ++jj)
                    acc[i][jj] = __builtin_amdgcn_mfma_f32_16x16x32_bf16(a[i], b[jj], acc[i][jj], 0, 0, 0);
        }
        __syncthreads();
    }
    #pragma unroll
    for (int i = 0; i < 4; ++i) {
        int rbase = m0 + wm * 64 + i * 16 + quad * 4;
        #pragma unroll
        for (int jj = 0; jj < 4; ++jj) {
            int c = n0 + wn * 64 + jj * 16 + l16;
            #pragma unroll
            for (int rr = 0; rr < 4; ++rr)
                Cout[(size_t)(rbase + rr) * POOL + c] = (bf16_t)acc[i][jj][rr];
        }
    }
}

// ---------------- rel_fused v2: occupancy-first streaming ----------------
// out = ((HW[i0]+TW[i1]+b_cat)*uni) @ Wctx + b_ctx + freq.
// 16 rows/block x 256 threads (4 waves), 8 KB LDS (dbuf Ss [16][128] bf16),
// acc = one f32x4/thread. launch_bounds(256,6) -> 84-VGPR cap, 6 blocks/CU,
// 24 waves/CU (75% occ). 2048 blocks. Single store per output (no atomics).

__global__ __launch_bounds__(256, 6) void rel_fused_kernel(
    const bf16_t* __restrict__ HWb,    // [8192][4096]
    const bf16_t* __restrict__ TWb,    // [8192][4096]
    const bf16_t* __restrict__ Wctx_t, // [64][4096] (rows 51..63 zero)
    const int* __restrict__ rel,       // [32768][2]
    const int* __restrict__ obj,       // [8192]
    const float* __restrict__ b_cat,   // [4096]
    const float* __restrict__ b_ctx,   // [51]
    const float* __restrict__ freq,    // [NOC*NOC][51]
    const float* __restrict__ uni,     // [32768][4096]
    float* __restrict__ out)           // [32768][51]
{
    __shared__ __align__(16) bf16_t Ss[2][16 * 128];   // 8 KB
    const int tid = threadIdx.x;
    const int w = tid >> 6, lane = tid & 63;
    const int quad = lane >> 4, l16 = lane & 15;
    const int lr = tid >> 4, hc = tid & 15;   // 16 rows x 16 col-chunks (8 cols each)
    const int m0 = blockIdx.x * 16;

    const int myrow = m0 + lr;
    const int gi0 = rel[2 * myrow], gi1 = rel[2 * myrow + 1];
    const bf16_t* hwrow = HWb + (size_t)gi0 * POOL;
    const bf16_t* twrow = TWb + (size_t)gi1 * POOL;
    const float*  urow  = uni + (size_t)myrow * POOL;

    f32x4 acc = {};

    auto scale_pass = [&](int kc, bf16_t* S) {
        const int cc = kc * 128 + hc * 8;
        bf16x8 hw = *(const bf16x8*)&hwrow[cc];
        bf16x8 tw = *(const bf16x8*)&twrow[cc];
        float4 u0 = *(const float4*)&urow[cc];
        float4 u1 = *(const float4*)&urow[cc + 4];
        float4 b0 = *(const float4*)&b_cat[cc];
        float4 b1 = *(const float4*)&b_cat[cc + 4];
        bf16x8 s;
        s[0] = (bf16_t)(((float)hw[0] + (float)tw[0] + b0.x) * u0.x);
        s[1] = (bf16_t)(((float)hw[1] + (float)tw[1] + b0.y) * u0.y);
        s[2] = (bf16_t)(((float)hw[2] + (float)tw[2] + b0.z) * u0.z);
        s[3] = (bf16_t)(((float)hw[3] + (float)tw[3] + b0.w) * u0.w);
        s[4] = (bf16_t)(((float)hw[4] + (float)tw[4] + b1.x) * u1.x);
        s[5] = (bf16_t)(((float)hw[5] + (float)tw[5] + b1.y) * u1.y);
        s[6] = (bf16_t)(((float)hw[6] + (float)tw[6] + b1.z) * u1.z);
        s[7] = (bf16_t)(((float)hw[7] + (float)tw[7] + b1.w) * u1.w);
        *(bf16x8*)&S[lr * 128 + ((hc ^ lr) << 3)] = s;     // XOR-swizzled 16B chunks
    };
    auto mma_pass = [&](int kc, const bf16_t* S) {
        #pragma unroll
        for (int kb = 0; kb < 4; ++kb) {       // K = 128 per chunk
            int m = l16;
            bf16x8 a2 = *(const bf16x8*)&S[m * 128 + (((kb * 4 + quad) ^ m) << 3)];
            int c = w * 16 + l16;              // class index 0..63
            bf16x8 b2 = *(const bf16x8*)&Wctx_t[(size_t)c * POOL + kc * 128 + kb * 32 + quad * 8];
            acc = __builtin_amdgcn_mfma_f32_16x16x32_bf16(a2, b2, acc, 0, 0, 0);
        }
    };

    scale_pass(0, Ss[0]);
    __syncthreads();
    for (int kc = 0; kc < 32; ++kc) {
        bf16_t* Scur = Ss[kc & 1];
        bf16_t* Snxt = Ss[(kc & 1) ^ 1];
        if (kc < 31) scale_pass(kc + 1, Snxt);   // global loads overlap mma of current
        mma_pass(kc, Scur);
        __syncthreads();
    }

    // Epilogue: fold b_ctx + freq gather, single store per output element.
    const int c = w * 16 + l16;
    if (c < NRC) {
        #pragma unroll
        for (int rr = 0; rr < 4; ++rr) {
            int row = m0 + quad * 4 + rr;
            int pid = obj[rel[2 * row]] * NOC + obj[rel[2 * row + 1]];
            out[(size_t)row * NRC + c] = acc[rr] + b_ctx[c] + freq[(size_t)pid * NRC + c];
        }
    }
}

// ---------------- launcher ----------------

extern "C" void kernel_launch(void* const* d_in, const int* in_sizes, int n_in,
                              void* d_out, int out_size, void* d_ws, size_t ws_size,
                              hipStream_t stream) {
    const float* edge_ctx = (const float*)d_in[0];
    const float* uni      = (const float*)d_in[1];
    const int*   rel      = (const int*)d_in[2];
    const int*   obj      = (const int*)d_in[3];
    const float* W_emb    = (const float*)d_in[4];
    const float* b_emb    = (const float*)d_in[5];
    const float* W_cat    = (const float*)d_in[6];
    const float* b_cat    = (const float*)d_in[7];
    const float* W_ctx    = (const float*)d_in[8];
    const float* b_ctx    = (const float*)d_in[9];
    const float* freq     = (const float*)d_in[10];
    float* out = (float*)d_out;

    char* p = (char*)d_ws;
    bf16_t* C1     = (bf16_t*)p; p += (size_t)N_OBJ * 1024 * 2;   // 16 MB
    bf16_t* ecb    = (bf16_t*)p; p += (size_t)N_OBJ * HID * 2;    //  8 MB
    bf16_t* Wemb_t = (bf16_t*)p; p += (size_t)1024 * HID * 2;     //  1 MB
    bf16_t* Wcat_t = (bf16_t*)p; p += (size_t)POOL * 1024 * 2;    //  8 MB
    bf16_t* Wctx_t = (bf16_t*)p; p += (size_t)64 * POOL * 2;      //  0.5 MB
    bf16_t* HWb    = (bf16_t*)p; p += (size_t)N_OBJ * POOL * 2;   // 64 MB
    bf16_t* TWb    = (bf16_t*)p; p += (size_t)N_OBJ * POOL * 2;   // 64 MB

    prep_kernel<<<6912, dim3(32, 8), 0, stream>>>(W_emb, Wemb_t, W_cat, Wcat_t,
                                                  W_ctx, Wctx_t, edge_ctx, ecb);
    gemm1_kernel<<<dim3(N_OBJ / 128, 1024 / 128), 256, 0, stream>>>(ecb, Wemb_t, b_emb, C1);
    gemm_half_kernel<<<dim3(N_OBJ / 128, POOL / 128, 2), 256, 0, stream>>>(C1, Wcat_t, HWb, TWb);
    rel_fused_kernel<<<N_REL / 16, 256, 0, stream>>>(HWb, TWb, Wctx_t, rel, obj,
                                                     b_cat, b_ctx, freq, uni, out);
}